// Round 12
// baseline (341.241 us; speedup 1.0000x reference)
//
#include <hip/hip_runtime.h>
#include <hip/hip_bf16.h>

#define NROWS 16384
#define DDIM  256
#define LOG2E 1.44269504088896f

typedef __attribute__((ext_vector_type(8))) short bh8;    // 8 x bf16 (4 VGPR)
typedef __attribute__((ext_vector_type(4))) short bh4;
typedef __attribute__((ext_vector_type(4))) float fx4;
typedef __attribute__((ext_vector_type(16))) float fx16;  // 32x32 accumulator

__device__ __forceinline__ short f2bf(float x) {
  __hip_bfloat16 h = __float2bfloat16(x);
  return *reinterpret_cast<short*>(&h);
}

__device__ __forceinline__ float fexp2(float x) {
#if __has_builtin(__builtin_amdgcn_exp2f)
  return __builtin_amdgcn_exp2f(x);   // v_exp_f32: D = 2^S0
#else
  return __expf(x * 0.6931471805599453f);
#endif
}

__device__ __forceinline__ fx16 fzero16() {
  fx16 z;
#pragma unroll
  for (int q = 0; q < 16; ++q) z[q] = 0.f;
  return z;
}

// exact softplus, used only on the 16384 diagonal elements
__device__ __forceinline__ float softplus_f(float y) {
  float a = fabsf(y);
  float t = __expf(-a);
  float l;
  if (t < 0.125f) {
    l = t * (1.0f - t * (0.5f - 0.333333333f * t));
  } else {
    l = log1pf(t);
  }
  return fmaxf(y, 0.0f) + l;
}

__global__ void cast_bf16_kernel(const float* __restrict__ in,
                                 unsigned short* __restrict__ out) {
  int i = (blockIdx.x * blockDim.x + threadIdx.x) * 8;
  float4 v0 = *(const float4*)(in + i);
  float4 v1 = *(const float4*)(in + i + 4);
  bh8 o;
  o[0] = f2bf(v0.x); o[1] = f2bf(v0.y); o[2] = f2bf(v0.z); o[3] = f2bf(v0.w);
  o[4] = f2bf(v1.x); o[5] = f2bf(v1.y); o[6] = f2bf(v1.z); o[7] = f2bf(v1.w);
  *(bh8*)((unsigned short*)out + i) = o;
}

// ============ persistent strip kernel: A-in-reg, paired-buffer schedule ====
// 512 blocks (2/CU), 256 threads = 4 waves (2 wr x 2 wc), wave tile 64x64 of
// mfma_f32_32x32x16_bf16 (2x2 fx16). Block = 128 img rows x 4096 txt cols.
// A resident in 128 regs/wave (areg[2][16], static indices, spill-free at
// this footprint per R10). B ring 4 x 16KB LDS; chunk = 128 cols x K=64.
// R11->R12 (registers reverted to R10 exactly): PAIR schedule. Pair A =
// chunks(kc 0,1) reading q0,q1; pair B = chunks(2,3) reading q2,q3. One
// vmcnt(0)+barrier per PAIR (64 barriers vs 128). During pair A, stage pair
// B's data into q2,q3 — never the buffers being read (WAR race that R10
// carried is structurally gone: q2/q3's previous readers completed via MFMA
// data-deps before reaching this pair's barrier). vmcnt(0) is cheap: the
// waited loads were issued one full pair (~3000cyc >> HBM latency) earlier.
// 32 MFMAs per pair give the scheduler a 2x window to sink chunk-1's reads
// under chunk-0's MFMAs (compiler-scheduled, per m97/m141 lessons).

// stage chunk (bt2,kc2) into buffer bufp (4 x global_load_lds / thread)
#define STAGE(bt2, kc2, bufp)                                                  \
  do {                                                                         \
    _Pragma("unroll")                                                          \
    for (int it_ = 0; it_ < 4; ++it_) {                                        \
      __builtin_amdgcn_global_load_lds(                                        \
          (const __attribute__((address_space(1))) void*)(                     \
              Bm + (size_t)(colgbase + (bt2) * 128 + it_ * 32 + colL) * DDIM + \
              (kc2) * 64 + kelemL),                                            \
          (__attribute__((address_space(3))) void*)((bufp) + it_ * 4096 +      \
                                                    wave * 1024 + lane * 16),  \
          16, 0, 0);                                                           \
    }                                                                          \
  } while (0)

// B k-slice offset within a col's 128B, swizzle folded: ((s*2+hi)^(lane&7))<<4
#define XS(s) ((((s) * 2 + hi) ^ le7) << 4)

// per-pair sync: wait the pair's two chunks (issued one pair ago), barrier,
// and forbid hoisting the pair's ds_reads above it.
#define PAIRSYNC()                                                             \
  do {                                                                         \
    asm volatile("s_waitcnt vmcnt(0)" ::: "memory");                           \
    __builtin_amdgcn_s_barrier();                                              \
    asm volatile("" ::: "memory");                                             \
  } while (0)

// one chunk body (no sync): 8 ds_read + optional stage + 16 MFMA
#define CHUNKB(kc, rbuf, DO_ST, SBT, SKC, sq)                                  \
  do {                                                                         \
    const char* bP_ = (rbuf) + bbase;                                          \
    bh8 b0A = *(const bh8*)(bP_ + XS(0));                                      \
    bh8 b0B = *(const bh8*)(bP_ + 4096 + XS(0));                               \
    bh8 b1A = *(const bh8*)(bP_ + XS(1));                                      \
    bh8 b1B = *(const bh8*)(bP_ + 4096 + XS(1));                               \
    bh8 b2A = *(const bh8*)(bP_ + XS(2));                                      \
    bh8 b2B = *(const bh8*)(bP_ + 4096 + XS(2));                               \
    bh8 b3A = *(const bh8*)(bP_ + XS(3));                                      \
    bh8 b3B = *(const bh8*)(bP_ + 4096 + XS(3));                               \
    if (DO_ST) STAGE(SBT, SKC, sq);                                            \
    acc00 = __builtin_amdgcn_mfma_f32_32x32x16_bf16(areg[0][(kc)*4+0], b0A, acc00, 0,0,0); \
    acc01 = __builtin_amdgcn_mfma_f32_32x32x16_bf16(areg[0][(kc)*4+0], b0B, acc01, 0,0,0); \
    acc10 = __builtin_amdgcn_mfma_f32_32x32x16_bf16(areg[1][(kc)*4+0], b0A, acc10, 0,0,0); \
    acc11 = __builtin_amdgcn_mfma_f32_32x32x16_bf16(areg[1][(kc)*4+0], b0B, acc11, 0,0,0); \
    acc00 = __builtin_amdgcn_mfma_f32_32x32x16_bf16(areg[0][(kc)*4+1], b1A, acc00, 0,0,0); \
    acc01 = __builtin_amdgcn_mfma_f32_32x32x16_bf16(areg[0][(kc)*4+1], b1B, acc01, 0,0,0); \
    acc10 = __builtin_amdgcn_mfma_f32_32x32x16_bf16(areg[1][(kc)*4+1], b1A, acc10, 0,0,0); \
    acc11 = __builtin_amdgcn_mfma_f32_32x32x16_bf16(areg[1][(kc)*4+1], b1B, acc11, 0,0,0); \
    acc00 = __builtin_amdgcn_mfma_f32_32x32x16_bf16(areg[0][(kc)*4+2], b2A, acc00, 0,0,0); \
    acc01 = __builtin_amdgcn_mfma_f32_32x32x16_bf16(areg[0][(kc)*4+2], b2B, acc01, 0,0,0); \
    acc10 = __builtin_amdgcn_mfma_f32_32x32x16_bf16(areg[1][(kc)*4+2], b2A, acc10, 0,0,0); \
    acc11 = __builtin_amdgcn_mfma_f32_32x32x16_bf16(areg[1][(kc)*4+2], b2B, acc11, 0,0,0); \
    acc00 = __builtin_amdgcn_mfma_f32_32x32x16_bf16(areg[0][(kc)*4+3], b3A, acc00, 0,0,0); \
    acc01 = __builtin_amdgcn_mfma_f32_32x32x16_bf16(areg[0][(kc)*4+3], b3B, acc01, 0,0,0); \
    acc10 = __builtin_amdgcn_mfma_f32_32x32x16_bf16(areg[1][(kc)*4+3], b3A, acc10, 0,0,0); \
    acc11 = __builtin_amdgcn_mfma_f32_32x32x16_bf16(areg[1][(kc)*4+3], b3B, acc11, 0,0,0); \
  } while (0)

// per-tile epilogue for one 32x32 acc; C layout (m74/m101):
// col = lane&31, row = (reg&3) + 8*(reg>>2) + 4*(lane>>5)
#define EPI32(A_, m_, n_)                                                      \
  do {                                                                         \
    fx16 v_ = A_;                                                              \
    A_ = fzero16();                                                            \
    _Pragma("unroll")                                                          \
    for (int g_ = 0; g_ < 16; g_ += 4) {                                       \
      e0 += fexp2(k1 * v_[g_ + 0]);                                            \
      e1 += fexp2(k1 * v_[g_ + 1]);                                            \
      e2 += fexp2(k1 * v_[g_ + 2]);                                            \
      e3 += fexp2(k1 * v_[g_ + 3]);                                            \
    }                                                                          \
    if (dtile) { /* block-uniform: at most 1 of 32 tiles */                    \
      const int gcol_ = colbase + wc * 64 + (n_) * 32 + (lane & 31);           \
      const int grow0_ = rowbase + wr * 64 + (m_) * 32 + 4 * hi;               \
      _Pragma("unroll")                                                        \
      for (int r_ = 0; r_ < 16; ++r_) {                                        \
        int grow_ = grow0_ + (r_ & 3) + 8 * (r_ >> 2);                         \
        if (grow_ == gcol_) {                                                  \
          d += softplus_f(-fmaf(scale, v_[r_], bias));                         \
          e0 -= fexp2(k1 * v_[r_]);                                            \
        }                                                                      \
      }                                                                        \
    }                                                                          \
  } while (0)

#define EPILOGUE(btv)                                                          \
  do {                                                                         \
    const int colbase = colgbase + (btv) * 128;                                \
    const bool dtile = (colbase == rowbase);                                   \
    EPI32(acc00, 0, 0); EPI32(acc01, 0, 1);                                    \
    EPI32(acc10, 1, 0); EPI32(acc11, 1, 1);                                    \
  } while (0)

__global__ __launch_bounds__(256, 2) void siglip_strip(
    const unsigned short* __restrict__ Am, const unsigned short* __restrict__ Bm,
    const float* __restrict__ scale_p, const float* __restrict__ bias_p,
    float* __restrict__ out) {
  __shared__ char lds[65536];    // B ring: 4 x 16KB
  char* q0 = lds;
  char* q1 = lds + 16384;
  char* q2 = lds + 32768;
  char* q3 = lds + 49152;

  const int tid  = threadIdx.x;
  const int lane = tid & 63;
  const int wave = tid >> 6;     // 0..3
  const int wr   = wave >> 1;    // 0..1
  const int wc   = wave & 1;     // 0..1
  // XCD-aware mapping: cg fixed per XCD (bid&7 = XCD on dispatch).
  const int bid  = blockIdx.x;
  const int rp   = ((bid >> 3) << 1) | (bid & 1);  // 0..127
  const int cg   = (bid >> 1) & 3;                 // 0..3
  const int rowbase  = rp * 128;
  const int colgbase = cg * 4096;

  // ---- per-lane constants ----
  const int hi  = lane >> 5;          // 0/1
  const int le7 = lane & 7;
  // staging: linear dest slot l*16 holds content (l*16) ^ ((l>>3)&7)<<4
  const int colL   = wave * 8 + (lane >> 3);                       // 0..31
  const int kelemL = (((lane & 7) * 16) ^ (((lane >> 3) & 7) << 4)) >> 1;
  // read base: col = wc*64 + n*32 + (lane&31), col stride 128B
  const int bbase = (wc * 64 + (lane & 31)) * 128;

  const float scale = *scale_p;   // uniform -> SGPR (lgkm domain)
  const float bias  = *bias_p;
  const float k1 = scale * LOG2E;
  const float eb = fexp2(bias * LOG2E);  // e^bias

  // ---- prologue: A slice into registers (32 x 16B loads, static indices) --
  bh8 areg[2][16];
  {
    const unsigned short* Aw = Am + (size_t)(rowbase + wr * 64) * DDIM;
#pragma unroll
    for (int m = 0; m < 2; ++m)
#pragma unroll
      for (int ks = 0; ks < 16; ++ks)
        areg[m][ks] = *(const bh8*)(Aw + (size_t)(m * 32 + (lane & 31)) * DDIM +
                                    ks * 16 + hi * 8);
  }
  // drain all prologue vmem so vmcnt below sees only staging loads
  asm volatile("s_waitcnt vmcnt(0)" ::: "memory");

  STAGE(0, 0, q0);  // pair A(0) data
  STAGE(0, 1, q1);

  fx16 acc00 = fzero16(), acc01 = fzero16();
  fx16 acc10 = fzero16(), acc11 = fzero16();
  float e0 = 0.f, e1 = 0.f, e2 = 0.f, e3 = 0.f, d = 0.f;

  for (int bt = 0; bt < 32; ++bt) {
    // ---- pair A: chunks (bt,0),(bt,1) from q0,q1; stage pair B -> q2,q3 ----
    PAIRSYNC();
    CHUNKB(0, q0, 1, bt, 2, q2);
    CHUNKB(1, q1, 1, bt, 3, q3);
    // ---- pair B: chunks (bt,2),(bt,3) from q2,q3; stage next pair A -------
    PAIRSYNC();
    if (bt < 31) {
      CHUNKB(2, q2, 1, bt + 1, 0, q0);
      CHUNKB(3, q3, 1, bt + 1, 1, q1);
    } else {
      CHUNKB(2, q2, 0, 0, 0, q0);
      CHUNKB(3, q3, 0, 0, 0, q1);
    }
    EPILOGUE(bt);  // register-only; overlaps next pair A's in-flight DMA
  }

  float local = fmaf((e0 + e1) + (e2 + e3), eb, d);
#pragma unroll
  for (int off = 32; off > 0; off >>= 1) local += __shfl_xor(local, off, 64);

  __syncthreads();  // LDS reuse for block reduction
  float* red = (float*)lds;
  if (lane == 0) red[wave] = local;
  __syncthreads();
  if (tid == 0)
    atomicAdd(out, ((red[0] + red[1]) + (red[2] + red[3])) * (1.0f / 16384.0f));
}

// ===================== fallback: f32 inputs, reg-staged (no ws needed) =====
__device__ __forceinline__ unsigned swz256(unsigned o) {
  return o ^ (((o >> 8) & 7u) << 4);
}

__device__ __forceinline__ void map_tile(int bid, int& tr, int& tc) {
  int xcd = bid & 7;
  int idx = bid >> 3;
  int g   = idx >> 7;
  int w   = idx & 127;
  tr = xcd * 16 + (w >> 3);
  tc = g * 8 + (w & 7);
}

__global__ __launch_bounds__(256, 2) void siglip_fallback(
    const float* __restrict__ A, const float* __restrict__ B,
    const float* __restrict__ scale_p, const float* __restrict__ bias_p,
    float* __restrict__ out) {
  __shared__ char lds[65536];
  char* ldsA = lds;
  char* ldsB = lds + 32768;
  const int tid  = threadIdx.x;
  const int lane = tid & 63;
  const int wave = tid >> 6;
  const int wr   = wave >> 1;
  const int wc   = wave & 1;
  int tr, tc;
  map_tile(blockIdx.x, tr, tc);
  const int brow = tr * 128, bcol = tc * 128;

  fx4 acc[4][4];
#pragma unroll
  for (int m = 0; m < 4; ++m)
#pragma unroll
    for (int n = 0; n < 4; ++n) acc[m][n] = (fx4){0.f, 0.f, 0.f, 0.f};

#pragma unroll
  for (int p = 0; p < 2; ++p) {
    __syncthreads();
    const float* Af = A + (size_t)brow * DDIM + p * 128;
    const float* Bf = B + (size_t)bcol * DDIM + p * 128;
#pragma unroll
    for (int it = 0; it < 16; ++it) {
      int c = it * 256 + tid;
      int row = c >> 5, j = c & 31;
      unsigned o = row * 256 + j * 8;
      {
        float4 v = *(const float4*)(Af + (size_t)row * DDIM + j * 4);
        bh4 h;
        h[0] = f2bf(v.x); h[1] = f2bf(v.y); h[2] = f2bf(v.z); h[3] = f2bf(v.w);
        *(bh4*)(ldsA + swz256(o)) = h;
      }
      {
        float4 v = *(const float4*)(Bf + (size_t)row * DDIM + j * 4);
        bh4 h;
        h[0] = f2bf(v.x); h[1] = f2bf(v.y); h[2] = f2bf(v.z); h[3] = f2bf(v.w);
        *(bh4*)(ldsB + swz256(o)) = h;
      }
    }
    __syncthreads();
#pragma unroll
    for (int kk = 0; kk < 4; ++kk) {
      const int colb = kk * 64 + (lane >> 4) * 16;
      bh8 a[4], b[4];
#pragma unroll
      for (int m = 0; m < 4; ++m) {
        int r = wr * 64 + m * 16 + (lane & 15);
        a[m] = *(const bh8*)(ldsA + swz256((unsigned)(r * 256 + colb)));
      }
#pragma unroll
      for (int n = 0; n < 4; ++n) {
        int r = wc * 64 + n * 16 + (lane & 15);
        b[n] = *(const bh8*)(ldsB + swz256((unsigned)(r * 256 + colb)));
      }
#pragma unroll
      for (int m = 0; m < 4; ++m)
#pragma unroll
        for (int n = 0; n < 4; ++n)
          acc[m][n] = __builtin_amdgcn_mfma_f32_16x16x32_bf16(a[m], b[n],
                                                              acc[m][n], 0, 0, 0);
    }
  }

  const float scale = *scale_p;
  const float bias  = *bias_p;
  const float k1 = scale * LOG2E;
  const float k0 = bias * LOG2E;
  float s0 = 0.f, s1 = 0.f, s2 = 0.f, s3 = 0.f;
  const int  row0 = brow + wr * 64 + (lane >> 4) * 4;
  const int  col0 = bcol + wc * 64 + (lane & 15);
  const bool isdiag = (tr == tc);
#pragma unroll
  for (int m = 0; m < 4; ++m) {
#pragma unroll
    for (int n = 0; n < 4; ++n) {
      fx4 v = acc[m][n];
      s0 += fexp2(fmaf(k1, v[0], k0));
      s1 += fexp2(fmaf(k1, v[1], k0));
      s2 += fexp2(fmaf(k1, v[2], k0));
      s3 += fexp2(fmaf(k1, v[3], k0));
      if (isdiag) {
        const int gj = col0 + n * 16;
#pragma unroll
        for (int j = 0; j < 4; ++j) {
          const int gi = row0 + m * 16 + j;
          if (gi == gj) {
            float logit = fmaf(scale, v[j], bias);
            s0 += softplus_f(-logit) - fexp2(fmaf(k1, v[j], k0));
          }
        }
      }
    }
  }
  float local = (s0 + s1) + (s2 + s3);
#pragma unroll
  for (int off = 32; off > 0; off >>= 1) local += __shfl_xor(local, off, 64);

  __syncthreads();
  float* red = (float*)lds;
  if (lane == 0) red[wave] = local;
  __syncthreads();
  if (tid == 0)
    atomicAdd(out, (red[0] + red[1] + red[2] + red[3]) * (1.0f / 16384.0f));
}

extern "C" void kernel_launch(void* const* d_in, const int* in_sizes, int n_in,
                              void* d_out, int out_size, void* d_ws,
                              size_t ws_size, hipStream_t stream) {
  const float* img     = (const float*)d_in[0];
  const float* txt     = (const float*)d_in[1];
  const float* scale_p = (const float*)d_in[2];
  const float* bias_p  = (const float*)d_in[3];
  float* out = (float*)d_out;

  hipMemsetAsync(d_out, 0, (size_t)out_size * sizeof(float), stream);

  const size_t elems = (size_t)NROWS * DDIM;
  const size_t need  = 2 * elems * sizeof(unsigned short);  // 16.8 MB

  if (ws_size >= need) {
    unsigned short* Abf = (unsigned short*)d_ws;
    unsigned short* Bbf = Abf + elems;
    const int cast_blocks = (int)(elems / (256 * 8));  // 2048
    cast_bf16_kernel<<<cast_blocks, 256, 0, stream>>>(img, Abf);
    cast_bf16_kernel<<<cast_blocks, 256, 0, stream>>>(txt, Bbf);
    siglip_strip<<<512, 256, 0, stream>>>(Abf, Bbf, scale_p, bias_p, out);
    return;
  }
  const int nblocks = (NROWS / 128) * (NROWS / 128);  // 16384
  siglip_fallback<<<nblocks, 256, 0, stream>>>(img, txt, scale_p, bias_p, out);
}

// Round 13
// 99.752 us; speedup vs baseline: 3.4209x; 3.4209x over previous
//
#include <hip/hip_runtime.h>
#include <hip/hip_bf16.h>
#include <hip/hip_fp8.h>

#define NROWS 16384
#define DDIM  256
#define LOG2E 1.44269504088896f

typedef __attribute__((ext_vector_type(8))) int ix8;      // 32B = 8 VGPR
typedef __attribute__((ext_vector_type(4))) short bh4;    // fallback use
typedef __attribute__((ext_vector_type(4))) float fx4;
typedef __attribute__((ext_vector_type(16))) float fx16;  // 32x32 accumulator

__device__ __forceinline__ short f2bf(float x) {
  __hip_bfloat16 h = __float2bfloat16(x);
  return *reinterpret_cast<short*>(&h);
}

__device__ __forceinline__ float fexp2(float x) {
#if __has_builtin(__builtin_amdgcn_exp2f)
  return __builtin_amdgcn_exp2f(x);   // v_exp_f32: D = 2^S0
#else
  return __expf(x * 0.6931471805599453f);
#endif
}

__device__ __forceinline__ fx16 fzero16() {
  fx16 z;
#pragma unroll
  for (int q = 0; q < 16; ++q) z[q] = 0.f;
  return z;
}

// exact softplus, used only on the 16384 diagonal elements
__device__ __forceinline__ float softplus_f(float y) {
  float a = fabsf(y);
  float t = __expf(-a);
  float l;
  if (t < 0.125f) {
    l = t * (1.0f - t * (0.5f - 0.333333333f * t));
  } else {
    l = log1pf(t);
  }
  return fmaxf(y, 0.0f) + l;
}

// fp32 -> fp8 e4m3 (OCP), 8 elements/thread
__global__ void cast_fp8_kernel(const float* __restrict__ in,
                                unsigned char* __restrict__ out) {
  int i = (blockIdx.x * blockDim.x + threadIdx.x) * 8;
  float4 v0 = *(const float4*)(in + i);
  float4 v1 = *(const float4*)(in + i + 4);
  unsigned r0 = (unsigned)__hip_fp8_e4m3(v0.x).__x |
                ((unsigned)__hip_fp8_e4m3(v0.y).__x << 8) |
                ((unsigned)__hip_fp8_e4m3(v0.z).__x << 16) |
                ((unsigned)__hip_fp8_e4m3(v0.w).__x << 24);
  unsigned r1 = (unsigned)__hip_fp8_e4m3(v1.x).__x |
                ((unsigned)__hip_fp8_e4m3(v1.y).__x << 8) |
                ((unsigned)__hip_fp8_e4m3(v1.z).__x << 16) |
                ((unsigned)__hip_fp8_e4m3(v1.w).__x << 24);
  uint2 r; r.x = r0; r.y = r1;
  *(uint2*)(out + i) = r;
}

// ============ persistent strip kernel: fp8 MX-scaled 32x32x64 =============
// 512 blocks (2/CU), 256 threads = 4 waves (2 wr x 2 wc), wave tile 64x64 of
// mfma_scale_f32_32x32x64_f8f6f4 (2x2 fx16, scale=1.0 in all bytes -> plain
// fp8 e4m3 GEMM at 2x bf16 rate). Block = 128 img rows x 4096 txt cols.
// A slice resident in 64 regs/wave (areg[2][4] ix8, static indices).
// LDS = 32KB: B ring 4 x 8KB; chunk = 128 cols x K=64 (fp8, 64B/col).
// Chunk t: [vmcnt(4) | barrier | fence | 2 ix8 LDS reads | STAGE(t+3) ->
// q[(t+3)%4] (!= read buffer q[t%4] -> WAR race of R10 removed) | 4 MFMA].
// K-layout note: A and B are loaded with IDENTICAL per-lane byte layouts
// (row/col = lane&31, bytes = k-range (lane>>5)*32..+31); any consistent
// k-permutation inside the operand is dot-product-invariant, and scale=1
// makes MX block assignment irrelevant -> layout risk collapses to the
// row/col convention already validated by the passing bf16 kernels.
// R11/R12 lesson: never make 2 chunks' B-frags co-live (spill); fp8 B-frags
// are 16 regs only and single-chunk-live here.

#define MFMA_SC(A_, B_, C_)                                                    \
  __builtin_amdgcn_mfma_scale_f32_32x32x64_f8f6f4((A_), (B_), (C_), 0, 0, 0,  \
                                                  sc1, 0, sc1)

// stage chunk (bt2,kc2) into buffer bufp (2 x global_load_lds / thread)
#define STAGE(bt2, kc2, bufp)                                                  \
  do {                                                                         \
    _Pragma("unroll")                                                          \
    for (int it_ = 0; it_ < 2; ++it_) {                                        \
      __builtin_amdgcn_global_load_lds(                                        \
          (const __attribute__((address_space(1))) void*)(                     \
              Bm +                                                             \
              (size_t)(colgbase + (bt2) * 128 + it_ * 64 + wave * 16 +         \
                       (lane >> 2)) * 256 +                                    \
              (kc2) * 64 + (lane & 3) * 16),                                   \
          (__attribute__((address_space(3))) void*)((bufp) + it_ * 4096 +      \
                                                    wave * 1024 + lane * 16),  \
          16, 0, 0);                                                           \
    }                                                                          \
  } while (0)

#define CHUNKF(kc, rbuf, VM, DO_ST, SBT, SKC, sq)                              \
  do {                                                                         \
    asm volatile("s_waitcnt vmcnt(%0)" ::"i"(VM) : "memory");                  \
    __builtin_amdgcn_s_barrier();                                              \
    asm volatile("" ::: "memory"); /* no LDS reads above the barrier */        \
    ix8 b0_ = *(const ix8*)((rbuf) + bb);                                      \
    ix8 b1_ = *(const ix8*)((rbuf) + 2048 + bb);                               \
    if (DO_ST) STAGE(SBT, SKC, sq);                                            \
    acc00 = MFMA_SC(areg[0][kc], b0_, acc00);                                  \
    acc01 = MFMA_SC(areg[0][kc], b1_, acc01);                                  \
    acc10 = MFMA_SC(areg[1][kc], b0_, acc10);                                  \
    acc11 = MFMA_SC(areg[1][kc], b1_, acc11);                                  \
  } while (0)

// per-tile epilogue for one 32x32 acc; C layout (m74/m101, shape-determined):
// col = lane&31, row = (reg&3) + 8*(reg>>2) + 4*(lane>>5)
#define EPI32(A_, m_, n_)                                                      \
  do {                                                                         \
    fx16 v_ = A_;                                                              \
    A_ = fzero16();                                                            \
    _Pragma("unroll")                                                          \
    for (int g_ = 0; g_ < 16; g_ += 4) {                                       \
      e0 += fexp2(k1 * v_[g_ + 0]);                                            \
      e1 += fexp2(k1 * v_[g_ + 1]);                                            \
      e2 += fexp2(k1 * v_[g_ + 2]);                                            \
      e3 += fexp2(k1 * v_[g_ + 3]);                                            \
    }                                                                          \
    if (dtile) { /* block-uniform: at most 1 of 32 tiles */                    \
      const int gcol_ = colbase + wc * 64 + (n_) * 32 + (lane & 31);           \
      const int grow0_ = rowbase + wr * 64 + (m_) * 32 + 4 * hi;               \
      _Pragma("unroll")                                                        \
      for (int r_ = 0; r_ < 16; ++r_) {                                        \
        int grow_ = grow0_ + (r_ & 3) + 8 * (r_ >> 2);                         \
        if (grow_ == gcol_) {                                                  \
          d += softplus_f(-fmaf(scale, v_[r_], bias));                         \
          e0 -= fexp2(k1 * v_[r_]);                                            \
        }                                                                      \
      }                                                                        \
    }                                                                          \
  } while (0)

#define EPILOGUE(btv)                                                          \
  do {                                                                         \
    const int colbase = colgbase + (btv) * 128;                                \
    const bool dtile = (colbase == rowbase);                                   \
    EPI32(acc00, 0, 0); EPI32(acc01, 0, 1);                                    \
    EPI32(acc10, 1, 0); EPI32(acc11, 1, 1);                                    \
  } while (0)

__global__ __launch_bounds__(256, 2) void siglip_strip(
    const unsigned char* __restrict__ Am, const unsigned char* __restrict__ Bm,
    const float* __restrict__ scale_p, const float* __restrict__ bias_p,
    float* __restrict__ out) {
  __shared__ char lds[32768];    // B ring: 4 x 8KB
  char* q0 = lds;
  char* q1 = lds + 8192;
  char* q2 = lds + 16384;
  char* q3 = lds + 24576;

  const int tid  = threadIdx.x;
  const int lane = tid & 63;
  const int wave = tid >> 6;     // 0..3
  const int wr   = wave >> 1;    // 0..1
  const int wc   = wave & 1;     // 0..1
  // XCD-aware mapping: cg fixed per XCD (bid&7 = XCD on dispatch).
  const int bid  = blockIdx.x;
  const int rp   = ((bid >> 3) << 1) | (bid & 1);  // 0..127
  const int cg   = (bid >> 1) & 3;                 // 0..3
  const int rowbase  = rp * 128;
  const int colgbase = cg * 4096;

  const int hi  = lane >> 5;          // 0/1
  // read base: col = wc*64 + n*32 + (lane&31); 64B/col; k-half by hi
  const int bb  = (wc * 64 + (lane & 31)) * 64 + hi * 32;
  const int sc1 = 0x7F7F7F7F;         // e8m0 scale 1.0 in every byte

  const float scale = *scale_p;   // uniform -> SGPR (lgkm domain)
  const float bias  = *bias_p;
  const float k1 = scale * LOG2E;
  const float eb = fexp2(bias * LOG2E);  // e^bias

  // ---- prologue: A slice into registers (8 x 32B loads, static indices) ---
  ix8 areg[2][4];
  {
    const unsigned char* Aw = Am + (size_t)(rowbase + wr * 64) * 256;
#pragma unroll
    for (int m = 0; m < 2; ++m)
#pragma unroll
      for (int kc = 0; kc < 4; ++kc)
        areg[m][kc] = *(const ix8*)(Aw + (size_t)(m * 32 + (lane & 31)) * 256 +
                                    kc * 64 + hi * 32);
  }
  // drain all prologue vmem so counted vmcnt below sees only staging loads
  asm volatile("s_waitcnt vmcnt(0)" ::: "memory");

  STAGE(0, 0, q0);  // chunk 0
  STAGE(0, 1, q1);  // chunk 1
  STAGE(0, 2, q2);  // chunk 2

  fx16 acc00 = fzero16(), acc01 = fzero16();
  fx16 acc10 = fzero16(), acc11 = fzero16();
  float e0 = 0.f, e1 = 0.f, e2 = 0.f, e3 = 0.f, d = 0.f;

  for (int bt = 0; bt < 31; ++bt) {
    CHUNKF(0, q0, 4, 1, bt,     3, q3);  // t=4bt+0, stage t+3 -> q3
    CHUNKF(1, q1, 4, 1, bt + 1, 0, q0);  // t=4bt+1, stage -> q0
    CHUNKF(2, q2, 4, 1, bt + 1, 1, q1);  // t=4bt+2, stage -> q1
    CHUNKF(3, q3, 4, 1, bt + 1, 2, q2);  // t=4bt+3, stage -> q2
    EPILOGUE(bt);  // register-only; overlaps in-flight DMA
  }
  // ---- peeled bt = 31 (chunks 124..127) ----
  CHUNKF(0, q0, 4, 1, 31, 3, q3);  // stage chunk 127
  CHUNKF(1, q1, 4, 0, 0, 0, q0);
  CHUNKF(2, q2, 2, 0, 0, 0, q0);
  CHUNKF(3, q3, 0, 0, 0, 0, q0);
  EPILOGUE(31);

  float local = fmaf((e0 + e1) + (e2 + e3), eb, d);
#pragma unroll
  for (int off = 32; off > 0; off >>= 1) local += __shfl_xor(local, off, 64);

  __syncthreads();  // LDS reuse for block reduction
  float* red = (float*)lds;
  if (lane == 0) red[wave] = local;
  __syncthreads();
  if (tid == 0)
    atomicAdd(out, ((red[0] + red[1]) + (red[2] + red[3])) * (1.0f / 16384.0f));
}

// ===================== fallback: f32 inputs, reg-staged (no ws needed) =====
__device__ __forceinline__ unsigned swz256(unsigned o) {
  return o ^ (((o >> 8) & 7u) << 4);
}

__device__ __forceinline__ void map_tile(int bid, int& tr, int& tc) {
  int xcd = bid & 7;
  int idx = bid >> 3;
  int g   = idx >> 7;
  int w   = idx & 127;
  tr = xcd * 16 + (w >> 3);
  tc = g * 8 + (w & 7);
}

typedef __attribute__((ext_vector_type(8))) short bh8;

__global__ __launch_bounds__(256, 2) void siglip_fallback(
    const float* __restrict__ A, const float* __restrict__ B,
    const float* __restrict__ scale_p, const float* __restrict__ bias_p,
    float* __restrict__ out) {
  __shared__ char lds[65536];
  char* ldsA = lds;
  char* ldsB = lds + 32768;
  const int tid  = threadIdx.x;
  const int lane = tid & 63;
  const int wave = tid >> 6;
  const int wr   = wave >> 1;
  const int wc   = wave & 1;
  int tr, tc;
  map_tile(blockIdx.x, tr, tc);
  const int brow = tr * 128, bcol = tc * 128;

  fx4 acc[4][4];
#pragma unroll
  for (int m = 0; m < 4; ++m)
#pragma unroll
    for (int n = 0; n < 4; ++n) acc[m][n] = (fx4){0.f, 0.f, 0.f, 0.f};

#pragma unroll
  for (int p = 0; p < 2; ++p) {
    __syncthreads();
    const float* Af = A + (size_t)brow * DDIM + p * 128;
    const float* Bf = B + (size_t)bcol * DDIM + p * 128;
#pragma unroll
    for (int it = 0; it < 16; ++it) {
      int c = it * 256 + tid;
      int row = c >> 5, j = c & 31;
      unsigned o = row * 256 + j * 8;
      {
        float4 v = *(const float4*)(Af + (size_t)row * DDIM + j * 4);
        bh4 h;
        h[0] = f2bf(v.x); h[1] = f2bf(v.y); h[2] = f2bf(v.z); h[3] = f2bf(v.w);
        *(bh4*)(ldsA + swz256(o)) = h;
      }
      {
        float4 v = *(const float4*)(Bf + (size_t)row * DDIM + j * 4);
        bh4 h;
        h[0] = f2bf(v.x); h[1] = f2bf(v.y); h[2] = f2bf(v.z); h[3] = f2bf(v.w);
        *(bh4*)(ldsB + swz256(o)) = h;
      }
    }
    __syncthreads();
#pragma unroll
    for (int kk = 0; kk < 4; ++kk) {
      const int colb = kk * 64 + (lane >> 4) * 16;
      bh8 a[4], b[4];
#pragma unroll
      for (int m = 0; m < 4; ++m) {
        int r = wr * 64 + m * 16 + (lane & 15);
        a[m] = *(const bh8*)(ldsA + swz256((unsigned)(r * 256 + colb)));
      }
#pragma unroll
      for (int n = 0; n < 4; ++n) {
        int r = wc * 64 + n * 16 + (lane & 15);
        b[n] = *(const bh8*)(ldsB + swz256((unsigned)(r * 256 + colb)));
      }
#pragma unroll
      for (int m = 0; m < 4; ++m)
#pragma unroll
        for (int n = 0; n < 4; ++n)
          acc[m][n] = __builtin_amdgcn_mfma_f32_16x16x32_bf16(a[m], b[n],
                                                              acc[m][n], 0, 0, 0);
    }
  }

  const float scale = *scale_p;
  const float bias  = *bias_p;
  const float k1 = scale * LOG2E;
  const float k0 = bias * LOG2E;
  float s0 = 0.f, s1 = 0.f, s2 = 0.f, s3 = 0.f;
  const int  row0 = brow + wr * 64 + (lane >> 4) * 4;
  const int  col0 = bcol + wc * 64 + (lane & 15);
  const bool isdiag = (tr == tc);
#pragma unroll
  for (int m = 0; m < 4; ++m) {
#pragma unroll
    for (int n = 0; n < 4; ++n) {
      fx4 v = acc[m][n];
      s0 += fexp2(fmaf(k1, v[0], k0));
      s1 += fexp2(fmaf(k1, v[1], k0));
      s2 += fexp2(fmaf(k1, v[2], k0));
      s3 += fexp2(fmaf(k1, v[3], k0));
      if (isdiag) {
        const int gj = col0 + n * 16;
#pragma unroll
        for (int j = 0; j < 4; ++j) {
          const int gi = row0 + m * 16 + j;
          if (gi == gj) {
            float logit = fmaf(scale, v[j], bias);
            s0 += softplus_f(-logit) - fexp2(fmaf(k1, v[j], k0));
          }
        }
      }
    }
  }
  float local = (s0 + s1) + (s2 + s3);
#pragma unroll
  for (int off = 32; off > 0; off >>= 1) local += __shfl_xor(local, off, 64);

  __syncthreads();
  float* red = (float*)lds;
  if (lane == 0) red[wave] = local;
  __syncthreads();
  if (tid == 0)
    atomicAdd(out, (red[0] + red[1] + red[2] + red[3]) * (1.0f / 16384.0f));
}

extern "C" void kernel_launch(void* const* d_in, const int* in_sizes, int n_in,
                              void* d_out, int out_size, void* d_ws,
                              size_t ws_size, hipStream_t stream) {
  const float* img     = (const float*)d_in[0];
  const float* txt     = (const float*)d_in[1];
  const float* scale_p = (const float*)d_in[2];
  const float* bias_p  = (const float*)d_in[3];
  float* out = (float*)d_out;

  hipMemsetAsync(d_out, 0, (size_t)out_size * sizeof(float), stream);

  const size_t elems = (size_t)NROWS * DDIM;               // 4.19M
  const size_t need  = 2 * elems * sizeof(unsigned char);  // 8.4 MB

  if (ws_size >= need) {
    unsigned char* A8 = (unsigned char*)d_ws;
    unsigned char* B8 = A8 + elems;
    const int cast_blocks = (int)(elems / (256 * 8));  // 2048
    cast_fp8_kernel<<<cast_blocks, 256, 0, stream>>>(img, A8);
    cast_fp8_kernel<<<cast_blocks, 256, 0, stream>>>(txt, B8);
    siglip_strip<<<512, 256, 0, stream>>>(A8, B8, scale_p, bias_p, out);
    return;
  }
  const int nblocks = (NROWS / 128) * (NROWS / 128);  // 16384
  siglip_fallback<<<nblocks, 256, 0, stream>>>(img, txt, scale_p, bias_p, out);
}

// Round 14
// 98.596 us; speedup vs baseline: 3.4610x; 1.0117x over previous
//
#include <hip/hip_runtime.h>
#include <hip/hip_bf16.h>
#include <hip/hip_fp8.h>

#define NROWS 16384
#define DDIM  256
#define LOG2E 1.44269504088896f

typedef __attribute__((ext_vector_type(8))) int ix8;      // 32B = 8 VGPR
typedef __attribute__((ext_vector_type(4))) short bh4;    // fallback use
typedef __attribute__((ext_vector_type(4))) float fx4;
typedef __attribute__((ext_vector_type(16))) float fx16;  // 32x32 accumulator

__device__ __forceinline__ short f2bf(float x) {
  __hip_bfloat16 h = __float2bfloat16(x);
  return *reinterpret_cast<short*>(&h);
}

__device__ __forceinline__ float fexp2(float x) {
#if __has_builtin(__builtin_amdgcn_exp2f)
  return __builtin_amdgcn_exp2f(x);   // v_exp_f32: D = 2^S0
#else
  return __expf(x * 0.6931471805599453f);
#endif
}

__device__ __forceinline__ fx16 fzero16() {
  fx16 z;
#pragma unroll
  for (int q = 0; q < 16; ++q) z[q] = 0.f;
  return z;
}

// exact softplus, used only on the 16384 diagonal elements
__device__ __forceinline__ float softplus_f(float y) {
  float a = fabsf(y);
  float t = __expf(-a);
  float l;
  if (t < 0.125f) {
    l = t * (1.0f - t * (0.5f - 0.333333333f * t));
  } else {
    l = log1pf(t);
  }
  return fmaxf(y, 0.0f) + l;
}

// fp32 -> fp8 e4m3 (OCP), 8 elements/thread
__global__ void cast_fp8_kernel(const float* __restrict__ in,
                                unsigned char* __restrict__ out) {
  int i = (blockIdx.x * blockDim.x + threadIdx.x) * 8;
  float4 v0 = *(const float4*)(in + i);
  float4 v1 = *(const float4*)(in + i + 4);
  unsigned r0 = (unsigned)__hip_fp8_e4m3(v0.x).__x |
                ((unsigned)__hip_fp8_e4m3(v0.y).__x << 8) |
                ((unsigned)__hip_fp8_e4m3(v0.z).__x << 16) |
                ((unsigned)__hip_fp8_e4m3(v0.w).__x << 24);
  unsigned r1 = (unsigned)__hip_fp8_e4m3(v1.x).__x |
                ((unsigned)__hip_fp8_e4m3(v1.y).__x << 8) |
                ((unsigned)__hip_fp8_e4m3(v1.z).__x << 16) |
                ((unsigned)__hip_fp8_e4m3(v1.w).__x << 24);
  uint2 r; r.x = r0; r.y = r1;
  *(uint2*)(out + i) = r;
}

// ============ persistent strip kernel: fp8 MX-scaled 32x32x64 =============
// 512 blocks (2/CU), 256 threads = 4 waves (2 wr x 2 wc), wave tile 64x64 of
// mfma_scale_f32_32x32x64_f8f6f4 (scale=1.0 -> plain fp8 e4m3 at 2x bf16
// rate). Block = 128 img rows x 4096 txt cols. A resident in 64 regs/wave.
// LDS = 32KB: B ring 4 x 8KB; chunk = 128 cols x K=64 (fp8, 64B/col).
// R13->R14: B LDS layout k-half-major. Per 4KB half-chunk region (64 cols):
//   offset(c, h, sub16) = h*2048 + c*32 + sub16*16   (was c*64 + h*32)
// Read base = wc*4096 + hi*2048 + (lane&31)*32 -> lane stride 32B -> start
// banks cycle {0,8,16,24}: all 32 banks tiled evenly, conflict-free (R13's
// col-major layout had 64B lane stride -> only banks {0,16} -> 1.26e7
// SQ_LDS_BANK_CONFLICT). Stage keeps linear dest (m173): the layout change
// lives entirely in the per-lane GLOBAL source address; source is still 32B
// contiguous per col and both 32B halves of each 64B sector are fetched by
// the block (waves 0,1 <-> h=0; waves 2,3 <-> h=1) -> no L2 over-fetch.
// Per-lane k-byte mapping of A and B identical -> dot-product invariant.

#define MFMA_SC(A_, B_, C_)                                                    \
  __builtin_amdgcn_mfma_scale_f32_32x32x64_f8f6f4((A_), (B_), (C_), 0, 0, 0,  \
                                                  sc1, 0, sc1)

// stage chunk (bt2,kc2) into buffer bufp (2 x global_load_lds / thread).
// dest slot (it*4096 + wave*1024 + lane*16) holds content:
//   h = wave>>1, c = (wave&1)*32 + (lane>>1), sub16 = lane&1
//   -> global col = bt2*128 + it*64 + c, kbyte = kc2*64 + h*32 + sub16*16
#define STAGE(bt2, kc2, bufp)                                                  \
  do {                                                                         \
    _Pragma("unroll")                                                          \
    for (int it_ = 0; it_ < 2; ++it_) {                                        \
      __builtin_amdgcn_global_load_lds(                                        \
          (const __attribute__((address_space(1))) void*)(                     \
              Bm +                                                             \
              (size_t)(colgbase + (bt2) * 128 + it_ * 64 + (wave & 1) * 32 +   \
                       (lane >> 1)) * 256 +                                    \
              (kc2) * 64 + (wave >> 1) * 32 + (lane & 1) * 16),                \
          (__attribute__((address_space(3))) void*)((bufp) + it_ * 4096 +      \
                                                    wave * 1024 + lane * 16),  \
          16, 0, 0);                                                           \
    }                                                                          \
  } while (0)

#define CHUNKF(kc, rbuf, VM, DO_ST, SBT, SKC, sq)                              \
  do {                                                                         \
    asm volatile("s_waitcnt vmcnt(%0)" ::"i"(VM) : "memory");                  \
    __builtin_amdgcn_s_barrier();                                              \
    asm volatile("" ::: "memory"); /* no LDS reads above the barrier */        \
    ix8 b0_ = *(const ix8*)((rbuf) + bb);                                      \
    ix8 b1_ = *(const ix8*)((rbuf) + 1024 + bb);                               \
    if (DO_ST) STAGE(SBT, SKC, sq);                                            \
    acc00 = MFMA_SC(areg[0][kc], b0_, acc00);                                  \
    acc01 = MFMA_SC(areg[0][kc], b1_, acc01);                                  \
    acc10 = MFMA_SC(areg[1][kc], b0_, acc10);                                  \
    acc11 = MFMA_SC(areg[1][kc], b1_, acc11);                                  \
  } while (0)

// per-tile epilogue for one 32x32 acc; C layout (m74/m101, shape-determined):
// col = lane&31, row = (reg&3) + 8*(reg>>2) + 4*(lane>>5)
#define EPI32(A_, m_, n_)                                                      \
  do {                                                                         \
    fx16 v_ = A_;                                                              \
    A_ = fzero16();                                                            \
    _Pragma("unroll")                                                          \
    for (int g_ = 0; g_ < 16; g_ += 4) {                                       \
      e0 += fexp2(k1 * v_[g_ + 0]);                                            \
      e1 += fexp2(k1 * v_[g_ + 1]);                                            \
      e2 += fexp2(k1 * v_[g_ + 2]);                                            \
      e3 += fexp2(k1 * v_[g_ + 3]);                                            \
    }                                                                          \
    if (dtile) { /* block-uniform: at most 1 of 32 tiles */                    \
      const int gcol_ = colbase + wc * 64 + (n_) * 32 + (lane & 31);           \
      const int grow0_ = rowbase + wr * 64 + (m_) * 32 + 4 * hi;               \
      _Pragma("unroll")                                                        \
      for (int r_ = 0; r_ < 16; ++r_) {                                        \
        int grow_ = grow0_ + (r_ & 3) + 8 * (r_ >> 2);                         \
        if (grow_ == gcol_) {                                                  \
          d += softplus_f(-fmaf(scale, v_[r_], bias));                         \
          e0 -= fexp2(k1 * v_[r_]);                                            \
        }                                                                      \
      }                                                                        \
    }                                                                          \
  } while (0)

#define EPILOGUE(btv)                                                          \
  do {                                                                         \
    const int colbase = colgbase + (btv) * 128;                                \
    const bool dtile = (colbase == rowbase);                                   \
    EPI32(acc00, 0, 0); EPI32(acc01, 0, 1);                                    \
    EPI32(acc10, 1, 0); EPI32(acc11, 1, 1);                                    \
  } while (0)

__global__ __launch_bounds__(256, 2) void siglip_strip(
    const unsigned char* __restrict__ Am, const unsigned char* __restrict__ Bm,
    const float* __restrict__ scale_p, const float* __restrict__ bias_p,
    float* __restrict__ out) {
  __shared__ char lds[32768];    // B ring: 4 x 8KB
  char* q0 = lds;
  char* q1 = lds + 8192;
  char* q2 = lds + 16384;
  char* q3 = lds + 24576;

  const int tid  = threadIdx.x;
  const int lane = tid & 63;
  const int wave = tid >> 6;     // 0..3
  const int wr   = wave >> 1;    // 0..1
  const int wc   = wave & 1;     // 0..1
  // XCD-aware mapping: cg fixed per XCD (bid&7 = XCD on dispatch).
  const int bid  = blockIdx.x;
  const int rp   = ((bid >> 3) << 1) | (bid & 1);  // 0..127
  const int cg   = (bid >> 1) & 3;                 // 0..3
  const int rowbase  = rp * 128;
  const int colgbase = cg * 4096;

  const int hi  = lane >> 5;          // 0/1
  // read base (k-half-major layout): wc*4096 + hi*2048 + (lane&31)*32;
  // n=0 at +0, n=1 at +1024. Lane stride 32B -> conflict-free.
  const int bb  = wc * 4096 + hi * 2048 + (lane & 31) * 32;
  const int sc1 = 0x7F7F7F7F;         // e8m0 scale 1.0 in every byte

  const float scale = *scale_p;   // uniform -> SGPR (lgkm domain)
  const float bias  = *bias_p;
  const float k1 = scale * LOG2E;
  const float eb = fexp2(bias * LOG2E);  // e^bias

  // ---- prologue: A slice into registers (8 x 32B loads, static indices) ---
  ix8 areg[2][4];
  {
    const unsigned char* Aw = Am + (size_t)(rowbase + wr * 64) * 256;
#pragma unroll
    for (int m = 0; m < 2; ++m)
#pragma unroll
      for (int kc = 0; kc < 4; ++kc)
        areg[m][kc] = *(const ix8*)(Aw + (size_t)(m * 32 + (lane & 31)) * 256 +
                                    kc * 64 + hi * 32);
  }
  // drain all prologue vmem so counted vmcnt below sees only staging loads
  asm volatile("s_waitcnt vmcnt(0)" ::: "memory");

  STAGE(0, 0, q0);  // chunk 0
  STAGE(0, 1, q1);  // chunk 1
  STAGE(0, 2, q2);  // chunk 2

  fx16 acc00 = fzero16(), acc01 = fzero16();
  fx16 acc10 = fzero16(), acc11 = fzero16();
  float e0 = 0.f, e1 = 0.f, e2 = 0.f, e3 = 0.f, d = 0.f;

  for (int bt = 0; bt < 31; ++bt) {
    CHUNKF(0, q0, 4, 1, bt,     3, q3);  // t=4bt+0, stage t+3 -> q3
    CHUNKF(1, q1, 4, 1, bt + 1, 0, q0);  // t=4bt+1, stage -> q0
    CHUNKF(2, q2, 4, 1, bt + 1, 1, q1);  // t=4bt+2, stage -> q1
    CHUNKF(3, q3, 4, 1, bt + 1, 2, q2);  // t=4bt+3, stage -> q2
    EPILOGUE(bt);  // register-only; overlaps in-flight DMA
  }
  // ---- peeled bt = 31 (chunks 124..127) ----
  CHUNKF(0, q0, 4, 1, 31, 3, q3);  // stage chunk 127
  CHUNKF(1, q1, 4, 0, 0, 0, q0);
  CHUNKF(2, q2, 2, 0, 0, 0, q0);
  CHUNKF(3, q3, 0, 0, 0, 0, q0);
  EPILOGUE(31);

  float local = fmaf((e0 + e1) + (e2 + e3), eb, d);
#pragma unroll
  for (int off = 32; off > 0; off >>= 1) local += __shfl_xor(local, off, 64);

  __syncthreads();  // LDS reuse for block reduction
  float* red = (float*)lds;
  if (lane == 0) red[wave] = local;
  __syncthreads();
  if (tid == 0)
    atomicAdd(out, ((red[0] + red[1]) + (red[2] + red[3])) * (1.0f / 16384.0f));
}

// ===================== fallback: f32 inputs, reg-staged (no ws needed) =====
__device__ __forceinline__ unsigned swz256(unsigned o) {
  return o ^ (((o >> 8) & 7u) << 4);
}

__device__ __forceinline__ void map_tile(int bid, int& tr, int& tc) {
  int xcd = bid & 7;
  int idx = bid >> 3;
  int g   = idx >> 7;
  int w   = idx & 127;
  tr = xcd * 16 + (w >> 3);
  tc = g * 8 + (w & 7);
}

typedef __attribute__((ext_vector_type(8))) short bh8;

__global__ __launch_bounds__(256, 2) void siglip_fallback(
    const float* __restrict__ A, const float* __restrict__ B,
    const float* __restrict__ scale_p, const float* __restrict__ bias_p,
    float* __restrict__ out) {
  __shared__ char lds[65536];
  char* ldsA = lds;
  char* ldsB = lds + 32768;
  const int tid  = threadIdx.x;
  const int lane = tid & 63;
  const int wave = tid >> 6;
  const int wr   = wave >> 1;
  const int wc   = wave & 1;
  int tr, tc;
  map_tile(blockIdx.x, tr, tc);
  const int brow = tr * 128, bcol = tc * 128;

  fx4 acc[4][4];
#pragma unroll
  for (int m = 0; m < 4; ++m)
#pragma unroll
    for (int n = 0; n < 4; ++n) acc[m][n] = (fx4){0.f, 0.f, 0.f, 0.f};

#pragma unroll
  for (int p = 0; p < 2; ++p) {
    __syncthreads();
    const float* Af = A + (size_t)brow * DDIM + p * 128;
    const float* Bf = B + (size_t)bcol * DDIM + p * 128;
#pragma unroll
    for (int it = 0; it < 16; ++it) {
      int c = it * 256 + tid;
      int row = c >> 5, j = c & 31;
      unsigned o = row * 256 + j * 8;
      {
        float4 v = *(const float4*)(Af + (size_t)row * DDIM + j * 4);
        bh4 h;
        h[0] = f2bf(v.x); h[1] = f2bf(v.y); h[2] = f2bf(v.z); h[3] = f2bf(v.w);
        *(bh4*)(ldsA + swz256(o)) = h;
      }
      {
        float4 v = *(const float4*)(Bf + (size_t)row * DDIM + j * 4);
        bh4 h;
        h[0] = f2bf(v.x); h[1] = f2bf(v.y); h[2] = f2bf(v.z); h[3] = f2bf(v.w);
        *(bh4*)(ldsB + swz256(o)) = h;
      }
    }
    __syncthreads();
#pragma unroll
    for (int kk = 0; kk < 4; ++kk) {
      const int colb = kk * 64 + (lane >> 4) * 16;
      bh8 a[4], b[4];
#pragma unroll
      for (int m = 0; m < 4; ++m) {
        int r = wr * 64 + m * 16 + (lane & 15);
        a[m] = *(const bh8*)(ldsA + swz256((unsigned)(r * 256 + colb)));
      }
#pragma unroll
      for (int n = 0; n < 4; ++n) {
        int r = wc * 64 + n * 16 + (lane & 15);
        b[n] = *(const bh8*)(ldsB + swz256((unsigned)(r * 256 + colb)));
      }
#pragma unroll
      for (int m = 0; m < 4; ++m)
#pragma unroll
        for (int n = 0; n < 4; ++n)
          acc[m][n] = __builtin_amdgcn_mfma_f32_16x16x32_bf16(a[m], b[n],
                                                              acc[m][n], 0, 0, 0);
    }
  }

  const float scale = *scale_p;
  const float bias  = *bias_p;
  const float k1 = scale * LOG2E;
  const float k0 = bias * LOG2E;
  float s0 = 0.f, s1 = 0.f, s2 = 0.f, s3 = 0.f;
  const int  row0 = brow + wr * 64 + (lane >> 4) * 4;
  const int  col0 = bcol + wc * 64 + (lane & 15);
  const bool isdiag = (tr == tc);
#pragma unroll
  for (int m = 0; m < 4; ++m) {
#pragma unroll
    for (int n = 0; n < 4; ++n) {
      fx4 v = acc[m][n];
      s0 += fexp2(fmaf(k1, v[0], k0));
      s1 += fexp2(fmaf(k1, v[1], k0));
      s2 += fexp2(fmaf(k1, v[2], k0));
      s3 += fexp2(fmaf(k1, v[3], k0));
      if (isdiag) {
        const int gj = col0 + n * 16;
#pragma unroll
        for (int j = 0; j < 4; ++j) {
          const int gi = row0 + m * 16 + j;
          if (gi == gj) {
            float logit = fmaf(scale, v[j], bias);
            s0 += softplus_f(-logit) - fexp2(fmaf(k1, v[j], k0));
          }
        }
      }
    }
  }
  float local = (s0 + s1) + (s2 + s3);
#pragma unroll
  for (int off = 32; off > 0; off >>= 1) local += __shfl_xor(local, off, 64);

  __syncthreads();
  float* red = (float*)lds;
  if (lane == 0) red[wave] = local;
  __syncthreads();
  if (tid == 0)
    atomicAdd(out, (red[0] + red[1] + red[2] + red[3]) * (1.0f / 16384.0f));
}

extern "C" void kernel_launch(void* const* d_in, const int* in_sizes, int n_in,
                              void* d_out, int out_size, void* d_ws,
                              size_t ws_size, hipStream_t stream) {
  const float* img     = (const float*)d_in[0];
  const float* txt     = (const float*)d_in[1];
  const float* scale_p = (const float*)d_in[2];
  const float* bias_p  = (const float*)d_in[3];
  float* out = (float*)d_out;

  hipMemsetAsync(d_out, 0, (size_t)out_size * sizeof(float), stream);

  const size_t elems = (size_t)NROWS * DDIM;               // 4.19M
  const size_t need  = 2 * elems * sizeof(unsigned char);  // 8.4 MB

  if (ws_size >= need) {
    unsigned char* A8 = (unsigned char*)d_ws;
    unsigned char* B8 = A8 + elems;
    const int cast_blocks = (int)(elems / (256 * 8));  // 2048
    cast_fp8_kernel<<<cast_blocks, 256, 0, stream>>>(img, A8);
    cast_fp8_kernel<<<cast_blocks, 256, 0, stream>>>(txt, B8);
    siglip_strip<<<512, 256, 0, stream>>>(A8, B8, scale_p, bias_p, out);
    return;
  }
  const int nblocks = (NROWS / 128) * (NROWS / 128);  // 16384
  siglip_fallback<<<nblocks, 256, 0, stream>>>(img, txt, scale_p, bias_p, out);
}

// Round 15
// 96.304 us; speedup vs baseline: 3.5434x; 1.0238x over previous
//
#include <hip/hip_runtime.h>
#include <hip/hip_bf16.h>
#include <hip/hip_fp8.h>

#define NROWS 16384
#define DDIM  256
#define LOG2E 1.44269504088896f

typedef __attribute__((ext_vector_type(8))) int ix8;      // 32B = 8 VGPR
typedef __attribute__((ext_vector_type(4))) short bh4;    // fallback use
typedef __attribute__((ext_vector_type(4))) float fx4;
typedef __attribute__((ext_vector_type(16))) float fx16;  // 32x32 accumulator

__device__ __forceinline__ short f2bf(float x) {
  __hip_bfloat16 h = __float2bfloat16(x);
  return *reinterpret_cast<short*>(&h);
}

__device__ __forceinline__ float fexp2(float x) {
#if __has_builtin(__builtin_amdgcn_exp2f)
  return __builtin_amdgcn_exp2f(x);   // v_exp_f32: D = 2^S0
#else
  return __expf(x * 0.6931471805599453f);
#endif
}

__device__ __forceinline__ fx16 fzero16() {
  fx16 z;
#pragma unroll
  for (int q = 0; q < 16; ++q) z[q] = 0.f;
  return z;
}

// exact softplus, used only on the 16384 diagonal elements
__device__ __forceinline__ float softplus_f(float y) {
  float a = fabsf(y);
  float t = __expf(-a);
  float l;
  if (t < 0.125f) {
    l = t * (1.0f - t * (0.5f - 0.333333333f * t));
  } else {
    l = log1pf(t);
  }
  return fmaxf(y, 0.0f) + l;
}

// fp32 -> fp8 e4m3 (OCP), 8 elements/thread
__global__ void cast_fp8_kernel(const float* __restrict__ in,
                                unsigned char* __restrict__ out) {
  int i = (blockIdx.x * blockDim.x + threadIdx.x) * 8;
  float4 v0 = *(const float4*)(in + i);
  float4 v1 = *(const float4*)(in + i + 4);
  unsigned r0 = (unsigned)__hip_fp8_e4m3(v0.x).__x |
                ((unsigned)__hip_fp8_e4m3(v0.y).__x << 8) |
                ((unsigned)__hip_fp8_e4m3(v0.z).__x << 16) |
                ((unsigned)__hip_fp8_e4m3(v0.w).__x << 24);
  unsigned r1 = (unsigned)__hip_fp8_e4m3(v1.x).__x |
                ((unsigned)__hip_fp8_e4m3(v1.y).__x << 8) |
                ((unsigned)__hip_fp8_e4m3(v1.z).__x << 16) |
                ((unsigned)__hip_fp8_e4m3(v1.w).__x << 24);
  uint2 r; r.x = r0; r.y = r1;
  *(uint2*)(out + i) = r;
}

// ============ persistent strip: fp8 MX 32x32x64 + B-frag register dbuf =====
// 512 blocks (2/CU), 256 threads = 4 waves (2 wr x 2 wc), wave tile 64x64 of
// mfma_scale_f32_32x32x64_f8f6f4 (scale=1.0 -> plain fp8 e4m3, 2x bf16 rate).
// Block = 128 img rows x 4096 txt cols. A resident in 64 regs/wave.
// LDS 32KB: B ring 4 x 8KB (k-half-major layout, conflict-minimal reads).
// R14->R15: B fragments double-buffered in REGISTERS (fe/fo, 16 regs each —
// affordable in fp8; the bf16 version of this spilled in R11). Chunk t:
//   [lgkm0 | vmcnt(4) | barrier | fence | READF frags(t+1) <- q[(t+1)%4] |
//    STAGE S(t+4) -> q[t%4] | 4 MFMA on frags(t), ZERO LDS dependency]
// - lgkm0: all waves' frag reads of q[t%4] (issued at chunk t-1) completed
//   before the barrier -> STAGE's DMA overwrite is WAR-safe.
// - vmcnt(4): S(t+1) has exactly 4 newer stage-ops outstanding -> landed.
//   (Also covers chunk 4bt+3 reading q0 staged by chunk 4bt.)
// - MFMA latency (550 cyc/SIMD for 2 waves) hides the reads+DMA issue.
// Register budget: areg 64 + acc 64 + frags 32 + misc ~20 = ~180 < 256.
// Watch WRITE_SIZE: MBs there = spill = revert (R11/R12 lesson).

#define MFMA_SC(A_, B_, C_)                                                    \
  __builtin_amdgcn_mfma_scale_f32_32x32x64_f8f6f4((A_), (B_), (C_), 0, 0, 0,  \
                                                  sc1, 0, sc1)

// stage chunk (bt2,kc2) into buffer bufp (2 x global_load_lds / thread).
// dest slot (it*4096 + wave*1024 + lane*16) holds content:
//   h = wave>>1, c = (wave&1)*32 + (lane>>1), sub16 = lane&1
#define STAGE(bt2, kc2, bufp)                                                  \
  do {                                                                         \
    _Pragma("unroll")                                                          \
    for (int it_ = 0; it_ < 2; ++it_) {                                        \
      __builtin_amdgcn_global_load_lds(                                        \
          (const __attribute__((address_space(1))) void*)(                     \
              Bm +                                                             \
              (size_t)(colgbase + (bt2) * 128 + it_ * 64 + (wave & 1) * 32 +   \
                       (lane >> 1)) * 256 +                                    \
              (kc2) * 64 + (wave >> 1) * 32 + (lane & 1) * 16),                \
          (__attribute__((address_space(3))) void*)((bufp) + it_ * 4096 +      \
                                                    wave * 1024 + lane * 16),  \
          16, 0, 0);                                                           \
    }                                                                          \
  } while (0)

// read the 2 B fragments of one chunk into register set P (P##0, P##1)
#define READF(P, qbuf)                                                         \
  do {                                                                         \
    P##0 = *(const ix8*)((qbuf) + bb);                                         \
    P##1 = *(const ix8*)((qbuf) + 1024 + bb);                                  \
  } while (0)

#define MFMAS(kc, P)                                                           \
  do {                                                                         \
    acc00 = MFMA_SC(areg[0][kc], P##0, acc00);                                 \
    acc01 = MFMA_SC(areg[0][kc], P##1, acc01);                                 \
    acc10 = MFMA_SC(areg[1][kc], P##0, acc10);                                 \
    acc11 = MFMA_SC(areg[1][kc], P##1, acc11);                                 \
  } while (0)

// one chunk position. CUR: frags consumed (chunk t, A k-page kc).
// NXT: frag set filled from qn (chunk t+1). Optional stage S(t+4) -> sq.
#define CHUNKP(kc, CUR, NXT, qn, VM, DO_RD, DO_ST, SBT, SKC, sq)               \
  do {                                                                         \
    asm volatile("s_waitcnt lgkmcnt(0)" ::: "memory");                         \
    asm volatile("s_waitcnt vmcnt(%0)" ::"i"(VM) : "memory");                  \
    __builtin_amdgcn_s_barrier();                                              \
    asm volatile("" ::: "memory"); /* no LDS reads above the barrier */        \
    if (DO_RD) READF(NXT, qn);                                                 \
    if (DO_ST) STAGE(SBT, SKC, sq);                                            \
    MFMAS(kc, CUR);                                                            \
  } while (0)

// per-tile epilogue for one 32x32 acc; C layout (m74/m101, shape-determined):
// col = lane&31, row = (reg&3) + 8*(reg>>2) + 4*(lane>>5)
#define EPI32(A_, m_, n_)                                                      \
  do {                                                                         \
    fx16 v_ = A_;                                                              \
    A_ = fzero16();                                                            \
    _Pragma("unroll")                                                          \
    for (int g_ = 0; g_ < 16; g_ += 4) {                                       \
      e0 += fexp2(k1 * v_[g_ + 0]);                                            \
      e1 += fexp2(k1 * v_[g_ + 1]);                                            \
      e2 += fexp2(k1 * v_[g_ + 2]);                                            \
      e3 += fexp2(k1 * v_[g_ + 3]);                                            \
    }                                                                          \
    if (dtile) { /* block-uniform: at most 1 of 32 tiles */                    \
      const int gcol_ = colbase + wc * 64 + (n_) * 32 + (lane & 31);           \
      const int grow0_ = rowbase + wr * 64 + (m_) * 32 + 4 * hi;               \
      _Pragma("unroll")                                                        \
      for (int r_ = 0; r_ < 16; ++r_) {                                        \
        int grow_ = grow0_ + (r_ & 3) + 8 * (r_ >> 2);                         \
        if (grow_ == gcol_) {                                                  \
          d += softplus_f(-fmaf(scale, v_[r_], bias));                         \
          e0 -= fexp2(k1 * v_[r_]);                                            \
        }                                                                      \
      }                                                                        \
    }                                                                          \
  } while (0)

#define EPILOGUE(btv)                                                          \
  do {                                                                         \
    const int colbase = colgbase + (btv) * 128;                                \
    const bool dtile = (colbase == rowbase);                                   \
    EPI32(acc00, 0, 0); EPI32(acc01, 0, 1);                                    \
    EPI32(acc10, 1, 0); EPI32(acc11, 1, 1);                                    \
  } while (0)

__global__ __launch_bounds__(256, 2) void siglip_strip(
    const unsigned char* __restrict__ Am, const unsigned char* __restrict__ Bm,
    const float* __restrict__ scale_p, const float* __restrict__ bias_p,
    float* __restrict__ out) {
  __shared__ char lds[32768];    // B ring: 4 x 8KB
  char* q0 = lds;
  char* q1 = lds + 8192;
  char* q2 = lds + 16384;
  char* q3 = lds + 24576;

  const int tid  = threadIdx.x;
  const int lane = tid & 63;
  const int wave = tid >> 6;     // 0..3
  const int wr   = wave >> 1;    // 0..1
  const int wc   = wave & 1;     // 0..1
  // XCD-aware mapping: cg fixed per XCD (bid&7 = XCD on dispatch).
  const int bid  = blockIdx.x;
  const int rp   = ((bid >> 3) << 1) | (bid & 1);  // 0..127
  const int cg   = (bid >> 1) & 3;                 // 0..3
  const int rowbase  = rp * 128;
  const int colgbase = cg * 4096;

  const int hi  = lane >> 5;          // 0/1
  // read base (k-half-major layout): wc*4096 + hi*2048 + (lane&31)*32;
  // n=0 at +0, n=1 at +1024. Lane stride 32B -> conflict-minimal.
  const int bb  = wc * 4096 + hi * 2048 + (lane & 31) * 32;
  const int sc1 = 0x7F7F7F7F;         // e8m0 scale 1.0 in every byte

  const float scale = *scale_p;   // uniform -> SGPR (lgkm domain)
  const float bias  = *bias_p;
  const float k1 = scale * LOG2E;
  const float eb = fexp2(bias * LOG2E);  // e^bias

  // ---- prologue: A slice into registers (8 x 32B loads, static indices) ---
  ix8 areg[2][4];
  {
    const unsigned char* Aw = Am + (size_t)(rowbase + wr * 64) * 256;
#pragma unroll
    for (int m = 0; m < 2; ++m)
#pragma unroll
      for (int kc = 0; kc < 4; ++kc)
        areg[m][kc] = *(const ix8*)(Aw + (size_t)(m * 32 + (lane & 31)) * 256 +
                                    kc * 64 + hi * 32);
  }
  // drain all prologue vmem so counted vmcnt below sees only staging loads
  asm volatile("s_waitcnt vmcnt(0)" ::: "memory");

  STAGE(0, 0, q0);  // S0
  STAGE(0, 1, q1);  // S1
  STAGE(0, 2, q2);  // S2
  STAGE(0, 3, q3);  // S3

  fx16 acc00 = fzero16(), acc01 = fzero16();
  fx16 acc10 = fzero16(), acc11 = fzero16();
  float e0 = 0.f, e1 = 0.f, e2 = 0.f, e3 = 0.f, d = 0.f;

  // B fragment register sets (even/odd chunks), 16 regs each
  ix8 fe0, fe1, fo0, fo1;

  // S0 landed (leave S1..S3 = 6 ops in flight); pre-read frags(0)
  asm volatile("s_waitcnt vmcnt(6)" ::: "memory");
  __builtin_amdgcn_s_barrier();
  asm volatile("" ::: "memory");
  READF(fe, q0);

  for (int bt = 0; bt < 31; ++bt) {
    CHUNKP(0, fe, fo, q1, 4, 1, 1, bt + 1, 0, q0);  // t=4bt+0, stage S(t+4)
    CHUNKP(1, fo, fe, q2, 4, 1, 1, bt + 1, 1, q1);  // t=4bt+1
    CHUNKP(2, fe, fo, q3, 4, 1, 1, bt + 1, 2, q2);  // t=4bt+2
    CHUNKP(3, fo, fe, q0, 4, 1, 1, bt + 1, 3, q3);  // t=4bt+3
    EPILOGUE(bt);  // register-only; overlaps in-flight DMA
  }
  // ---- peeled bt = 31 (chunks 124..127; no further staging) ----
  CHUNKP(0, fe, fo, q1, 4, 1, 0, 0, 0, q0);  // t=124, frags(125); S126,S127 out
  CHUNKP(1, fo, fe, q2, 2, 1, 0, 0, 0, q0);  // t=125, frags(126); S127 out
  CHUNKP(2, fe, fo, q3, 0, 1, 0, 0, 0, q0);  // t=126, frags(127)
  MFMAS(3, fo);                              // t=127 (frags already in regs)
  EPILOGUE(31);

  float local = fmaf((e0 + e1) + (e2 + e3), eb, d);
#pragma unroll
  for (int off = 32; off > 0; off >>= 1) local += __shfl_xor(local, off, 64);

  __syncthreads();  // LDS reuse for block reduction
  float* red = (float*)lds;
  if (lane == 0) red[wave] = local;
  __syncthreads();
  if (tid == 0)
    atomicAdd(out, ((red[0] + red[1]) + (red[2] + red[3])) * (1.0f / 16384.0f));
}

// ===================== fallback: f32 inputs, reg-staged (no ws needed) =====
__device__ __forceinline__ unsigned swz256(unsigned o) {
  return o ^ (((o >> 8) & 7u) << 4);
}

__device__ __forceinline__ void map_tile(int bid, int& tr, int& tc) {
  int xcd = bid & 7;
  int idx = bid >> 3;
  int g   = idx >> 7;
  int w   = idx & 127;
  tr = xcd * 16 + (w >> 3);
  tc = g * 8 + (w & 7);
}

typedef __attribute__((ext_vector_type(8))) short bh8;

__global__ __launch_bounds__(256, 2) void siglip_fallback(
    const float* __restrict__ A, const float* __restrict__ B,
    const float* __restrict__ scale_p, const float* __restrict__ bias_p,
    float* __restrict__ out) {
  __shared__ char lds[65536];
  char* ldsA = lds;
  char* ldsB = lds + 32768;
  const int tid  = threadIdx.x;
  const int lane = tid & 63;
  const int wave = tid >> 6;
  const int wr   = wave >> 1;
  const int wc   = wave & 1;
  int tr, tc;
  map_tile(blockIdx.x, tr, tc);
  const int brow = tr * 128, bcol = tc * 128;

  fx4 acc[4][4];
#pragma unroll
  for (int m = 0; m < 4; ++m)
#pragma unroll
    for (int n = 0; n < 4; ++n) acc[m][n] = (fx4){0.f, 0.f, 0.f, 0.f};

#pragma unroll
  for (int p = 0; p < 2; ++p) {
    __syncthreads();
    const float* Af = A + (size_t)brow * DDIM + p * 128;
    const float* Bf = B + (size_t)bcol * DDIM + p * 128;
#pragma unroll
    for (int it = 0; it < 16; ++it) {
      int c = it * 256 + tid;
      int row = c >> 5, j = c & 31;
      unsigned o = row * 256 + j * 8;
      {
        float4 v = *(const float4*)(Af + (size_t)row * DDIM + j * 4);
        bh4 h;
        h[0] = f2bf(v.x); h[1] = f2bf(v.y); h[2] = f2bf(v.z); h[3] = f2bf(v.w);
        *(bh4*)(ldsA + swz256(o)) = h;
      }
      {
        float4 v = *(const float4*)(Bf + (size_t)row * DDIM + j * 4);
        bh4 h;
        h[0] = f2bf(v.x); h[1] = f2bf(v.y); h[2] = f2bf(v.z); h[3] = f2bf(v.w);
        *(bh4*)(ldsB + swz256(o)) = h;
      }
    }
    __syncthreads();
#pragma unroll
    for (int kk = 0; kk < 4; ++kk) {
      const int colb = kk * 64 + (lane >> 4) * 16;
      bh8 a[4], b[4];
#pragma unroll
      for (int m = 0; m < 4; ++m) {
        int r = wr * 64 + m * 16 + (lane & 15);
        a[m] = *(const bh8*)(ldsA + swz256((unsigned)(r * 256 + colb)));
      }
#pragma unroll
      for (int n = 0; n < 4; ++n) {
        int r = wc * 64 + n * 16 + (lane & 15);
        b[n] = *(const bh8*)(ldsB + swz256((unsigned)(r * 256 + colb)));
      }
#pragma unroll
      for (int m = 0; m < 4; ++m)
#pragma unroll
        for (int n = 0; n < 4; ++n)
          acc[m][n] = __builtin_amdgcn_mfma_f32_16x16x32_bf16(a[m], b[n],
                                                              acc[m][n], 0, 0, 0);
    }
  }

  const float scale = *scale_p;
  const float bias  = *bias_p;
  const float k1 = scale * LOG2E;
  const float k0 = bias * LOG2E;
  float s0 = 0.f, s1 = 0.f, s2 = 0.f, s3 = 0.f;
  const int  row0 = brow + wr * 64 + (lane >> 4) * 4;
  const int  col0 = bcol + wc * 64 + (lane & 15);
  const bool isdiag = (tr == tc);
#pragma unroll
  for (int m = 0; m < 4; ++m) {
#pragma unroll
    for (int n = 0; n < 4; ++n) {
      fx4 v = acc[m][n];
      s0 += fexp2(fmaf(k1, v[0], k0));
      s1 += fexp2(fmaf(k1, v[1], k0));
      s2 += fexp2(fmaf(k1, v[2], k0));
      s3 += fexp2(fmaf(k1, v[3], k0));
      if (isdiag) {
        const int gj = col0 + n * 16;
#pragma unroll
        for (int j = 0; j < 4; ++j) {
          const int gi = row0 + m * 16 + j;
          if (gi == gj) {
            float logit = fmaf(scale, v[j], bias);
            s0 += softplus_f(-logit) - fexp2(fmaf(k1, v[j], k0));
          }
        }
      }
    }
  }
  float local = (s0 + s1) + (s2 + s3);
#pragma unroll
  for (int off = 32; off > 0; off >>= 1) local += __shfl_xor(local, off, 64);

  __syncthreads();
  float* red = (float*)lds;
  if (lane == 0) red[wave] = local;
  __syncthreads();
  if (tid == 0)
    atomicAdd(out, (red[0] + red[1] + red[2] + red[3]) * (1.0f / 16384.0f));
}

extern "C" void kernel_launch(void* const* d_in, const int* in_sizes, int n_in,
                              void* d_out, int out_size, void* d_ws,
                              size_t ws_size, hipStream_t stream) {
  const float* img     = (const float*)d_in[0];
  const float* txt     = (const float*)d_in[1];
  const float* scale_p = (const float*)d_in[2];
  const float* bias_p  = (const float*)d_in[3];
  float* out = (float*)d_out;

  hipMemsetAsync(d_out, 0, (size_t)out_size * sizeof(float), stream);

  const size_t elems = (size_t)NROWS * DDIM;               // 4.19M
  const size_t need  = 2 * elems * sizeof(unsigned char);  // 8.4 MB

  if (ws_size >= need) {
    unsigned char* A8 = (unsigned char*)d_ws;
    unsigned char* B8 = A8 + elems;
    const int cast_blocks = (int)(elems / (256 * 8));  // 2048
    cast_fp8_kernel<<<cast_blocks, 256, 0, stream>>>(img, A8);
    cast_fp8_kernel<<<cast_blocks, 256, 0, stream>>>(txt, B8);
    siglip_strip<<<512, 256, 0, stream>>>(A8, B8, scale_p, bias_p, out);
    return;
  }
  const int nblocks = (NROWS / 128) * (NROWS / 128);  // 16384
  siglip_fallback<<<nblocks, 256, 0, stream>>>(img, txt, scale_p, bias_p, out);
}